// Round 5
// baseline (761.517 us; speedup 1.0000x reference)
//
#include <hip/hip_runtime.h>

#define HID 256
#define OBS 1024
#define SEQ 50
#define BATCH 32
#define SO (SEQ*OBS)   // 51200

struct DevWS {
  float ub[2][HID][HID];    // normalized reflectors (bitrev order)
  float C2[2][HID][HID];    // reflector Gram (symmetric)
  float ZT[2][HID][HID];    // row k = z_k
  float U[HID][HID];
  float V[HID][HID];
  float A[HID][HID];
  float A2[HID][HID];
  float A4[HID][HID];
  float A8[HID][HID];
  float A16[HID][HID];
  float A32[HID][HID];
  float Cg[HID][HID];       // C^T C  (= G_1)
  float G2[HID][HID];
  float Grun[HID][HID];
  float T[HID][HID];
  float T2[HID][HID];
  float G18[HID][HID];
  float G32b[HID][HID];
  float Gfin[HID][HID];
  float Zt[SEQ][HID*BATCH];    // Z_t = C^T Y^T_t
  float Rb[2][25][HID*BATCH];  // R-tree ping-pong
  float psum[1025];            // y^2 partials [0..1023], logdet^2 [1024]
  float s1b[32];               // per-b  sum_j alpha_j * rz_j
};
__device__ DevWS g;

__device__ __forceinline__ float* sel(int c){
  switch(c){
    case 0:  return &g.ub[0][0][0];
    case 1:  return &g.ub[1][0][0];
    case 4:  return &g.C2[0][0][0];
    case 5:  return &g.C2[1][0][0];
    case 6:  return &g.ZT[0][0][0];
    case 7:  return &g.ZT[1][0][0];
    case 8:  return &g.U[0][0];
    case 9:  return &g.V[0][0];
    case 10: return &g.A[0][0];
    case 11: return &g.A2[0][0];
    case 12: return &g.A4[0][0];
    case 13: return &g.A8[0][0];
    case 14: return &g.A16[0][0];
    case 15: return &g.A32[0][0];
    case 16: return &g.Cg[0][0];
    case 17: return &g.G2[0][0];
    case 18: return &g.Grun[0][0];
    case 19: return &g.T[0][0];
    case 20: return &g.T2[0][0];
    case 21: return &g.G18[0][0];
    case 22: return &g.G32b[0][0];
    case 23: return &g.Gfin[0][0];
    case 24: return &g.Zt[0][0];
    case 25: return &g.Rb[0][0][0];
    default: return &g.Rb[1][0][0];
  }
}

__device__ __forceinline__ int bitrev8(int x){
  x = ((x & 0x55) << 1) | ((x >> 1) & 0x55);
  x = ((x & 0x33) << 2) | ((x >> 2) & 0x33);
  x = ((x & 0x0F) << 4) | ((x >> 4) & 0x0F);
  return x;
}

// ================= k_prep: normalize | y^2 psum | logdet psum | C^T C ========
__global__ __launch_bounds__(256) void k_prep(const float* __restrict__ y,
                                              const float* __restrict__ logdet,
                                              const float* __restrict__ Up,
                                              const float* __restrict__ Vp,
                                              const float* __restrict__ Cm){
  __shared__ float As[16][36];
  __shared__ float Bs[16][36];
  __shared__ float red[256];
  const int bx = blockIdx.x;
  const int t = threadIdx.x;
  if(bx < 512){
    int mat = bx >> 8, j = bx & 255;
    int src = bitrev8(j);
    const float* P = mat ? Vp : Up;
    float x = P[src*HID + t];
    red[t] = x*x; __syncthreads();
    for(int s=128; s>0; s>>=1){ if(t<s) red[t]+=red[t+s]; __syncthreads(); }
    g.ub[mat][j][t] = x * rsqrtf(red[0]);
    return;
  }
  if(bx < 1536){
    int bi = bx - 512;
    const float4* y4 = reinterpret_cast<const float4*>(y);
    const int n4 = (BATCH*SO)/4;
    float s = 0.f;
    for(int i = bi*256 + t; i < n4; i += 1024*256){
      float4 v = y4[i];
      s += v.x*v.x + v.y*v.y + v.z*v.z + v.w*v.w;
    }
    red[t] = s; __syncthreads();
    for(int st=128; st>0; st>>=1){ if(t<st) red[t]+=red[t+st]; __syncthreads(); }
    if(t==0) g.psum[bi] = red[0];
    return;
  }
  if(bx == 1536){
    float s = 0.f;
    for(int i = t; i < BATCH*SEQ; i += 256){ float v = logdet[i]; s += v*v; }
    red[t] = s; __syncthreads();
    for(int st=128; st>0; st>>=1){ if(t<st) red[t]+=red[t+st]; __syncthreads(); }
    if(t==0) g.psum[1024] = red[0];
    return;
  }
  {
    int tile = bx - 1537;
    int tx = t & 15, ty = t >> 4;
    int m0 = (tile>>3)*32, n0 = (tile&7)*32;
    float acc[2][2] = {{0.f,0.f},{0.f,0.f}};
    for(int o0=0; o0<OBS; o0+=16){
      int r = t>>4, cp = (t&15)*2;
      float2 a = *reinterpret_cast<const float2*>(&Cm[(o0+r)*HID + m0 + cp]);
      As[r][cp] = a.x; As[r][cp+1] = a.y;
      float2 b = *reinterpret_cast<const float2*>(&Cm[(o0+r)*HID + n0 + cp]);
      Bs[r][cp] = b.x; Bs[r][cp+1] = b.y;
      __syncthreads();
      #pragma unroll
      for(int kk=0; kk<16; kk++){
        float a0 = As[kk][ty*2], a1 = As[kk][ty*2+1];
        float b0 = Bs[kk][tx*2], b1 = Bs[kk][tx*2+1];
        acc[0][0]+=a0*b0; acc[0][1]+=a0*b1; acc[1][0]+=a1*b0; acc[1][1]+=a1*b1;
      }
      __syncthreads();
    }
    #pragma unroll
    for(int i2=0;i2<2;i2++)
    #pragma unroll
    for(int j2=0;j2<2;j2++)
      g.Cg[m0+ty*2+i2][n0+tx*2+j2] = acc[i2][j2];
  }
}

// ================= Z_t = C^T Y^T_t for all t =================
__global__ __launch_bounds__(1024) void k_CtY(const float* __restrict__ y,
                                              const float* __restrict__ C){
  const int tt = blockIdx.x;
  __shared__ float ys[256][36];
  const int h = threadIdx.x >> 2, bq = threadIdx.x & 3;
  float acc[8] = {0,0,0,0,0,0,0,0};
  for(int ot=0; ot<4; ot++){
    for(int e=threadIdx.x; e<32*256; e+=1024){
      int b = e>>8, o = e&255;
      ys[o][b] = y[b*SO + tt*OBS + ot*256 + o];
    }
    __syncthreads();
    for(int o=0; o<256; o++){
      float cv = C[(ot*256+o)*HID + h];
      float4 v0 = *reinterpret_cast<const float4*>(&ys[o][bq*8]);
      float4 v1 = *reinterpret_cast<const float4*>(&ys[o][bq*8+4]);
      acc[0]+=cv*v0.x; acc[1]+=cv*v0.y; acc[2]+=cv*v0.z; acc[3]+=cv*v0.w;
      acc[4]+=cv*v1.x; acc[5]+=cv*v1.y; acc[6]+=cv*v1.z; acc[7]+=cv*v1.w;
    }
    __syncthreads();
  }
  #pragma unroll
  for(int j=0;j<8;j++) g.Zt[tt][h*32 + bq*8 + j] = acc[j];
}

// ================= WY, all-on-chip =================
// z_k = 2u_k - 2*sum_{i<k} z_i C2[k][i]
// thread (q=t>>8, d=t&255) keeps cross-panel accum wacc[j] for k=64q+j in regs
__global__ __launch_bounds__(1024) void k_wy(){
  const int m = blockIdx.x;
  const int t = threadIdx.x;
  const int d = t & 255;
  const int q = t >> 8;
  __shared__ float c2ft[256][32];  // [k_global][i_local]: C2[k][k0+i] (symmetric)
  __shared__ float zsd[256][36];   // [d][k_local] current panel Z (f4-aligned rows)
  __shared__ float ubs[32][256];   // [k_local][d]
  __shared__ float ws[32][256];    // [k_local][d] cross-panel prefix
  float wacc[64];
  #pragma unroll
  for(int j=0;j<64;j++) wacc[j]=0.f;
  const float* C2m = &g.C2[m][0][0];
  const float* ubm = &g.ub[m][0][0];

  for(int p=0;p<8;p++){
    const int k0 = p*32;
    // stage c2ft[k][i] = C2[k][k0+i]  (coalesced; rows broadcast-read later)
    for(int e=t;e<8192;e+=1024){
      int k=e>>5, i=e&31;
      c2ft[k][i] = C2m[k*HID + k0 + i];
    }
    // stage ubs
    for(int e=t;e<8192;e+=1024){
      int kl=e>>8, dd=e&255;
      ubs[kl][dd] = ubm[(k0+kl)*HID + dd];
    }
    // owners publish prefix (static wacc indices in both branches)
    if(q == (p>>1)){
      if(p & 1){
        #pragma unroll
        for(int kl=0;kl<32;kl++) ws[kl][d] = wacc[32+kl];
      } else {
        #pragma unroll
        for(int kl=0;kl<32;kl++) ws[kl][d] = wacc[kl];
      }
    }
    __syncthreads();
    // in-panel serial solve (256 threads, all operands in LDS)
    if(t < 256){
      #pragma unroll
      for(int k=0;k<32;k++){
        float acc = 0.f;
        #pragma unroll
        for(int j0=0;j0+4<=k;j0+=4){
          float4 cz = *reinterpret_cast<const float4*>(&c2ft[k0+k][j0]);
          float4 zz = *reinterpret_cast<const float4*>(&zsd[d][j0]);
          acc += cz.x*zz.x + cz.y*zz.y + cz.z*zz.z + cz.w*zz.w;
        }
        #pragma unroll
        for(int j=(k&~3);j<k;j++) acc += c2ft[k0+k][j]*zsd[d][j];
        float z = 2.f*(ubs[k][d] - ws[k][d] - acc);
        zsd[d][k] = z;
        g.ZT[m][k0+k][d] = z;     // fire-and-forget for U/V GEMM
      }
    }
    __syncthreads();
    // rank-32 update of register accumulators (future k only)
    if(p < 7){
      const int kfirst = k0 + 32;
      #pragma unroll
      for(int i0=0;i0<32;i0+=8){
        float4 za = *reinterpret_cast<const float4*>(&zsd[d][i0]);
        float4 zb = *reinterpret_cast<const float4*>(&zsd[d][i0+4]);
        #pragma unroll
        for(int j=0;j<64;j++){
          int k = q*64 + j;
          if(k >= kfirst){
            float4 ca = *reinterpret_cast<const float4*>(&c2ft[k][i0]);
            float4 cb = *reinterpret_cast<const float4*>(&c2ft[k][i0+4]);
            wacc[j] += ca.x*za.x+ca.y*za.y+ca.z*za.z+ca.w*za.w
                     + cb.x*zb.x+cb.y*zb.y+cb.z*zb.z+cb.w*zb.w;
          }
        }
      }
    }
    __syncthreads();
  }
}

// ================= generic batched GEMM =================
#define F_TRANSA   1
#define F_NEGID    2
#define F_ACC      4
#define F_TRANSB   8
#define F_SCALECOL 16
#define F_RLEVEL   32
#define F_GDBL     64

struct GD { int cA, cB, cC, cD, flags, npair; };
struct GArgs { GD d[4]; int pre[4]; int nd; };

__global__ __launch_bounds__(256) void k_gemmN(GArgs ga, const float* __restrict__ alpha){
  int blk = blockIdx.x;
  int di = 0;
  #pragma unroll
  for(int s=1;s<4;s++) if(ga.nd > s && blk >= ga.pre[s]) di = s;
  const GD d = ga.d[di];
  const int local = blk - ga.pre[di];
  const int t = threadIdx.x;
  const int tx = t & 15, ty = t >> 4;
  __shared__ float sm[13408];   // 53.6 KB carved per-path
  #define AS(a,b) sm[(a)*36+(b)]
  #define BS(a,b) sm[576+(a)*36+(b)]

  if(d.flags & F_GDBL){
    // out = E + X^T G X  (G symmetric), tile (m0,n0)
    const float* X  = sel(d.cA);
    const float* Gm = sel(d.cB);
    float* Outp = sel(d.cC);
    const float* E  = sel(d.cD);
    float* Ws = sm;            // [256][34]
    float* Gs = sm + 8704;     // [16][258]
    float* Xb = sm + 12832;    // [16][36]
    const int m0=(local>>3)*32, n0=(local&7)*32;
    float accW[8][4];
    #pragma unroll
    for(int r=0;r<8;r++){ accW[r][0]=0.f;accW[r][1]=0.f;accW[r][2]=0.f;accW[r][3]=0.f; }
    for(int k0=0;k0<HID;k0+=16){
      for(int e=t;e<4096;e+=256){ int kk=e>>8, r=e&255; Gs[kk*258+r] = Gm[(k0+kk)*HID + r]; }
      for(int e=t;e<512;e+=256){ int kk=e>>5, c=e&31; Xb[kk*36+c] = X[(k0+kk)*HID + n0 + c]; }
      __syncthreads();
      #pragma unroll
      for(int kk=0;kk<16;kk++){
        float b0 = Xb[kk*36+tx*2], b1 = Xb[kk*36+tx*2+1];
        #pragma unroll
        for(int r0=0;r0<8;r0++){
          float a0 = Gs[kk*258 + r0*32 + ty*2];
          float a1 = Gs[kk*258 + r0*32 + ty*2 + 1];
          accW[r0][0]+=a0*b0; accW[r0][1]+=a0*b1; accW[r0][2]+=a1*b0; accW[r0][3]+=a1*b1;
        }
      }
      __syncthreads();
    }
    #pragma unroll
    for(int r0=0;r0<8;r0++){
      Ws[(r0*32+ty*2)*34 + tx*2]     = accW[r0][0];
      Ws[(r0*32+ty*2)*34 + tx*2+1]   = accW[r0][1];
      Ws[(r0*32+ty*2+1)*34 + tx*2]   = accW[r0][2];
      Ws[(r0*32+ty*2+1)*34 + tx*2+1] = accW[r0][3];
    }
    __syncthreads();
    float acc2[4]={0.f,0.f,0.f,0.f};
    for(int k0=0;k0<HID;k0+=16){
      for(int e=t;e<512;e+=256){ int kk=e>>5, mm=e&31; Xb[kk*36+mm] = X[(k0+kk)*HID + m0 + mm]; }
      __syncthreads();
      #pragma unroll
      for(int kk=0;kk<16;kk++){
        float a0 = Xb[kk*36+ty*2], a1 = Xb[kk*36+ty*2+1];
        float b0 = Ws[(k0+kk)*34 + tx*2], b1 = Ws[(k0+kk)*34 + tx*2+1];
        acc2[0]+=a0*b0; acc2[1]+=a0*b1; acc2[2]+=a1*b0; acc2[3]+=a1*b1;
      }
      __syncthreads();
    }
    const int r=m0+ty*2, c=n0+tx*2;
    Outp[r*HID+c]       = E[r*HID+c]       + acc2[0];
    Outp[r*HID+c+1]     = E[r*HID+c+1]     + acc2[1];
    Outp[(r+1)*HID+c]   = E[(r+1)*HID+c]   + acc2[2];
    Outp[(r+1)*HID+c+1] = E[(r+1)*HID+c+1] + acc2[3];
    return;
  }

  if(d.flags & F_RLEVEL){
    const float* P  = sel(d.cA);
    const float* In = sel(d.cB);
    float* Out = sel(d.cC);
    const int j = local >> 3, mt = local & 7;
    if(j >= d.npair){
      const float* src = In + (size_t)(2*j)*(HID*BATCH) + mt*1024;
      float* dst = Out + (size_t)j*(HID*BATCH) + mt*1024;
      *reinterpret_cast<float4*>(dst + t*4) = *reinterpret_cast<const float4*>(src + t*4);
      return;
    }
    const float* B1 = In + (size_t)(2*j+1)*(HID*BATCH);
    const float* D0 = In + (size_t)(2*j)*(HID*BATCH);
    float* C0 = Out + (size_t)j*(HID*BATCH);
    const int m0 = mt*32;
    float acc[2][2] = {{0.f,0.f},{0.f,0.f}};
    for(int k0=0; k0<HID; k0+=16){
      { int kk=t>>4, mm=(t&15)*2;
        float2 a = *reinterpret_cast<const float2*>(&P[(k0+kk)*HID + m0+mm]);
        AS(kk,mm)=a.x; AS(kk,mm+1)=a.y; }
      { int rb=t>>4, cb=(t&15)*2;
        float2 b = *reinterpret_cast<const float2*>(&B1[(k0+rb)*BATCH + cb]);
        BS(rb,cb)=b.x; BS(rb,cb+1)=b.y; }
      __syncthreads();
      #pragma unroll
      for(int kk=0; kk<16; kk++){
        float a0=AS(kk,ty*2), a1=AS(kk,ty*2+1);
        float b0=BS(kk,tx*2), b1=BS(kk,tx*2+1);
        acc[0][0]+=a0*b0; acc[0][1]+=a0*b1; acc[1][0]+=a1*b0; acc[1][1]+=a1*b1;
      }
      __syncthreads();
    }
    #pragma unroll
    for(int i2=0;i2<2;i2++)
    #pragma unroll
    for(int j2=0;j2<2;j2++){
      int r=m0+ty*2+i2, c=tx*2+j2;
      C0[r*BATCH+c] = D0[r*BATCH+c] + acc[i2][j2];
    }
    return;
  }

  // square 256x256x256
  const float* A = sel(d.cA);
  const float* B = sel(d.cB);
  float* Cp = sel(d.cC);
  const float* Dp = sel(d.cD);
  const int m0 = (local>>3)*32, n0 = (local&7)*32;
  float acc[2][2] = {{0.f,0.f},{0.f,0.f}};
  for(int k0=0; k0<HID; k0+=16){
    if(d.flags & F_TRANSA){
      int kk=t>>4, mm=(t&15)*2;
      float2 a = *reinterpret_cast<const float2*>(&A[(k0+kk)*HID + m0+mm]);
      AS(kk,mm)=a.x; AS(kk,mm+1)=a.y;
    } else {
      int r=t>>3, c=(t&7)*2;
      float2 a = *reinterpret_cast<const float2*>(&A[(m0+r)*HID + k0+c]);
      AS(c,r)=a.x; AS(c+1,r)=a.y;
    }
    if(d.flags & F_TRANSB){
      int cb=t>>3, rb=(t&7)*2;
      float2 v = *reinterpret_cast<const float2*>(&B[(n0+cb)*HID + k0+rb]);
      BS(rb,cb)=v.x; BS(rb+1,cb)=v.y;
    } else {
      int rb=t>>4, cb=(t&15)*2;
      float2 b = *reinterpret_cast<const float2*>(&B[(k0+rb)*HID + n0+cb]);
      BS(rb,cb)=b.x; BS(rb,cb+1)=b.y;
    }
    __syncthreads();
    #pragma unroll
    for(int kk=0; kk<16; kk++){
      float a0=AS(kk,ty*2), a1=AS(kk,ty*2+1);
      float b0=BS(kk,tx*2), b1=BS(kk,tx*2+1);
      acc[0][0]+=a0*b0; acc[0][1]+=a0*b1; acc[1][0]+=a1*b0; acc[1][1]+=a1*b1;
    }
    __syncthreads();
  }
  float sc0=1.f, sc1=1.f;
  if(d.flags & F_SCALECOL){
    sc0 = 1.0f - fminf(fabsf(alpha[n0+tx*2]),   1.0f);
    sc1 = 1.0f - fminf(fabsf(alpha[n0+tx*2+1]), 1.0f);
  }
  #pragma unroll
  for(int i2=0;i2<2;i2++)
  #pragma unroll
  for(int j2=0;j2<2;j2++){
    int r=m0+ty*2+i2, c=n0+tx*2+j2;
    float v = acc[i2][j2];
    if(d.flags & F_ACC) v += Dp[r*HID+c];
    if(d.flags & F_SCALECOL) v *= (j2 ? sc1 : sc0);
    if(d.flags & F_NEGID) v = (r==c ? 1.0f : 0.0f) - v;
    Cp[r*HID+c] = v;
  }
  #undef AS
  #undef BS
}

// ================= CG solve: 8 blocks x 4 RHS, G in registers =================
#define CG_ITERS 10
__global__ __launch_bounds__(1024) void k_cg(){
  const int tid = threadIdx.x;
  const int i = tid & 255;
  const int q = tid >> 8;
  const int lane = tid & 63;
  const int wv = tid >> 6;
  const int b0 = blockIdx.x * 4;
  __shared__ float p_s[256][4];
  __shared__ float partf[4][256][4];
  __shared__ float red1[16];
  __shared__ float s_rz[4], s_pap[4], s_rzn[4], s_be[4], s_s1[4];

  float gr[64];
  const float* Gf = &g.Gfin[0][0];
  #pragma unroll
  for(int j=0;j<64;j++) gr[j] = Gf[(64*q+j)*HID + i];
  const float dinv = 1.0f / Gf[i*(HID+1)];

  float rcur = g.Rb[1][0][i*BATCH + b0 + q];
  p_s[i][q] = rcur*dinv;
  if(tid<4) s_s1[tid]=0.f;
  __syncthreads();

  {
    float v = dinv*rcur*rcur;
    v+=__shfl_down(v,32);v+=__shfl_down(v,16);v+=__shfl_down(v,8);
    v+=__shfl_down(v,4);v+=__shfl_down(v,2);v+=__shfl_down(v,1);
    if(lane==0) red1[wv]=v;
    __syncthreads();
    if(tid<4) s_rz[tid]=red1[tid*4]+red1[tid*4+1]+red1[tid*4+2]+red1[tid*4+3];
    __syncthreads();
  }

  for(int it=0; it<CG_ITERS; it++){
    float pa0=0.f,pa1=0.f,pa2=0.f,pa3=0.f;
    #pragma unroll
    for(int j=0;j<64;j++){
      const float4 pv = *reinterpret_cast<const float4*>(&p_s[64*q+j][0]);
      const float gv = gr[j];
      pa0 = fmaf(gv,pv.x,pa0); pa1 = fmaf(gv,pv.y,pa1);
      pa2 = fmaf(gv,pv.z,pa2); pa3 = fmaf(gv,pv.w,pa3);
    }
    float4 w4; w4.x=pa0; w4.y=pa1; w4.z=pa2; w4.w=pa3;
    *reinterpret_cast<float4*>(&partf[q][i][0]) = w4;
    __syncthreads();
    const float ap = partf[0][i][q]+partf[1][i][q]+partf[2][i][q]+partf[3][i][q];
    const float pvl = p_s[i][q];
    {
      float v = pvl*ap;
      v+=__shfl_down(v,32);v+=__shfl_down(v,16);v+=__shfl_down(v,8);
      v+=__shfl_down(v,4);v+=__shfl_down(v,2);v+=__shfl_down(v,1);
      if(lane==0) red1[wv]=v;
      __syncthreads();
      if(tid<4) s_pap[tid]=red1[tid*4]+red1[tid*4+1]+red1[tid*4+2]+red1[tid*4+3];
      __syncthreads();
    }
    const float al = s_rz[q]/fmaxf(s_pap[q],1e-30f);
    rcur = rcur - al*ap;
    {
      float v = dinv*rcur*rcur;
      v+=__shfl_down(v,32);v+=__shfl_down(v,16);v+=__shfl_down(v,8);
      v+=__shfl_down(v,4);v+=__shfl_down(v,2);v+=__shfl_down(v,1);
      if(lane==0) red1[wv]=v;
      __syncthreads();
      if(tid<4) s_rzn[tid]=red1[tid*4]+red1[tid*4+1]+red1[tid*4+2]+red1[tid*4+3];
      __syncthreads();
    }
    if(tid<4){
      const float alb = s_rz[tid]/fmaxf(s_pap[tid],1e-30f);
      s_s1[tid] += alb*s_rz[tid];
      s_be[tid]  = s_rzn[tid]/fmaxf(s_rz[tid],1e-30f);
      s_rz[tid]  = s_rzn[tid];
    }
    __syncthreads();
    p_s[i][q] = dinv*rcur + s_be[q]*p_s[i][q];
    __syncthreads();
  }
  if(tid<4) g.s1b[b0+tid] = s_s1[tid];
}

// ================= final loss =================
__global__ __launch_bounds__(256) void k_fin(float* __restrict__ out){
  const int t = threadIdx.x;
  __shared__ float red[4];
  float s = g.psum[t] + g.psum[t+256] + g.psum[t+512] + g.psum[t+768];
  s += __shfl_down(s,32); s += __shfl_down(s,16); s += __shfl_down(s,8);
  s += __shfl_down(s,4);  s += __shfl_down(s,2);  s += __shfl_down(s,1);
  if((t&63)==0) red[t>>6]=s;
  __syncthreads();
  if(t==0){
    float sy2 = red[0]+red[1]+red[2]+red[3];
    float t1 = 0.f;
    for(int b=0;b<32;b++) t1 += g.s1b[b];
    float sld = g.psum[1024];
    float mw = (sy2 - t1) / (float)(SO*BATCH);
    out[0] = 0.5f*mw + sld / ((float)(BATCH*SEQ) * (float)OBS * (float)OBS);
  }
}

// ================= host side =================
struct LB { GArgs ga; int total; };
static inline GD sq(int cA,int cB,int cC,int cD,int flags){ GD d; d.cA=cA;d.cB=cB;d.cC=cC;d.cD=cD;d.flags=flags;d.npair=0; return d; }
static inline GD gdb(int cX,int cG,int cOut,int cE){ GD d; d.cA=cX;d.cB=cG;d.cC=cOut;d.cD=cE;d.flags=F_GDBL;d.npair=0; return d; }
static inline GD rl(int cP,int cin,int cout,int npair){ GD d; d.cA=cP;d.cB=cin;d.cC=cout;d.cD=0;d.flags=F_RLEVEL;d.npair=npair; return d; }
static inline LB mkN(const GD* ds, const int* bs, int n){
  LB l; int acc=0;
  for(int i=0;i<4;i++){ l.ga.pre[i]=0; }
  for(int i=0;i<n;i++){ l.ga.d[i]=ds[i]; l.ga.pre[i]=acc; acc+=bs[i]; }
  l.ga.nd=n; l.total=acc; return l;
}

extern "C" void kernel_launch(void* const* d_in, const int* in_sizes, int n_in,
                              void* d_out, int out_size, void* d_ws, size_t ws_size,
                              hipStream_t stream){
  const float* y      = (const float*)d_in[0];
  const float* logdet = (const float*)d_in[1];
  const float* Up     = (const float*)d_in[2];
  const float* Vp     = (const float*)d_in[3];
  const float* alpha  = (const float*)d_in[4];
  const float* Cm     = (const float*)d_in[5];
  float* out = (float*)d_out;

  k_prep<<<dim3(1601), dim3(256), 0, stream>>>(y, logdet, Up, Vp, Cm);
  k_CtY<<<dim3(SEQ), dim3(1024), 0, stream>>>(y, Cm);
  { GD ds[2]={sq(0,0,4,4,F_TRANSB), sq(1,1,5,5,F_TRANSB)}; int bs[2]={64,64};     // C2_U, C2_V
    LB l=mkN(ds,bs,2); k_gemmN<<<l.total,256,0,stream>>>(l.ga, alpha); }
  k_wy<<<dim3(2), dim3(1024), 0, stream>>>();
  { GD ds[2]={sq(6,0,8,8,F_TRANSA|F_NEGID), sq(7,1,9,9,F_TRANSA|F_NEGID)}; int bs[2]={64,64}; // U,V
    LB l=mkN(ds,bs,2); k_gemmN<<<l.total,256,0,stream>>>(l.ga, alpha); }
  { GD ds[1]={sq(8,9,10,10,F_TRANSB|F_SCALECOL)}; int bs[1]={64};                 // A = (U V^T)*S
    LB l=mkN(ds,bs,1); k_gemmN<<<l.total,256,0,stream>>>(l.ga, alpha); }
  // L1: A2=A*A ; G2 = Cg + A^T Cg A ; Rlvl1 (25 pairs, P=A)
  { GD ds[3]={sq(10,10,11,0,0), gdb(10,16,17,16), rl(10,24,25,25)}; int bs[3]={64,64,200};
    LB l=mkN(ds,bs,3); k_gemmN<<<l.total,256,0,stream>>>(l.ga, alpha); }
  // L2: A4 ; G4 = G2 + A2^T G2 A2 ; Rlvl2 (12+1, P=A2)
  { GD ds[3]={sq(11,11,12,0,0), gdb(11,17,18,17), rl(11,25,26,12)}; int bs[3]={64,64,104};
    LB l=mkN(ds,bs,3); k_gemmN<<<l.total,256,0,stream>>>(l.ga, alpha); }
  // L3: A8 ; G8 = G4 + A4^T G4 A4 ; Rlvl3 (6+1, P=A4)
  { GD ds[3]={sq(12,12,13,0,0), gdb(12,18,19,18), rl(12,26,25,6)}; int bs[3]={64,64,56};
    LB l=mkN(ds,bs,3); k_gemmN<<<l.total,256,0,stream>>>(l.ga, alpha); }
  // L4: A16 ; G16 = G8 + A8^T G8 A8 ; Rlvl4 (3+1, P=A8)
  { GD ds[3]={sq(13,13,14,0,0), gdb(13,19,18,19), rl(13,25,26,3)}; int bs[3]={64,64,32};
    LB l=mkN(ds,bs,3); k_gemmN<<<l.total,256,0,stream>>>(l.ga, alpha); }
  // L5: A32 ; G32 = G16 + A16^T G16 A16 ; G18 = G16 + A16^T G2 A16 ; Rlvl5 (2, P=A16)
  { GD ds[4]={sq(14,14,15,0,0), gdb(14,18,22,18), gdb(14,17,21,18), rl(14,26,25,2)}; int bs[4]={64,64,64,16};
    LB l=mkN(ds,bs,4); k_gemmN<<<l.total,256,0,stream>>>(l.ga, alpha); }
  // L6: G50 = G32 + A32^T G18 A32 ; Rlvl6 (1, P=A32)
  { GD ds[2]={gdb(15,21,23,22), rl(15,25,26,1)}; int bs[2]={64,8};
    LB l=mkN(ds,bs,2); k_gemmN<<<l.total,256,0,stream>>>(l.ga, alpha); }

  k_cg<<<dim3(8), dim3(1024), 0, stream>>>();
  k_fin<<<dim3(1), dim3(256), 0, stream>>>(out);
}